// Round 6
// baseline (171.010 us; speedup 1.0000x reference)
//
#include <hip/hip_runtime.h>
#include <math.h>

#define N_NODES 50000
#define N_EDGES 800000
#define NFEAT 256
#define NHID 64
#define NCLASS 2

// buckets: node>>6 -> 782 buckets of 64 nodes
#define DB 64
#define NDB 782
#define BCAP 1536        // csr per-bucket spacing (mean 1024, +16 sigma)
#define EPB 4096         // edges per scatter chunk (16/thread) -> 196 chunks
#define NB_EDGE ((N_EDGES + EPB - 1) / EPB)
#define NSUB 16          // sub-cursors per bucket: atomic chain ~12
#define SUBCAP 160       // per-(bucket,sub) slots: mean ~65, +11 sigma
#define CSTR 8           // cursor padding: 4 counters per 128B line

// ---------------- workspace layout (4-byte units) ----------------
#define OFF_CURD 0         // int[NDB*NSUB*CSTR = 100096]
#define OFF_CURS 100096    // int[100096]
#define OFF_RBD  200192    // int2[50000] (row_beg, deg)
#define OFF_NDST 300192    // f32[50000]
#define OFF_NSRC 350192    // f32[50000]
#define OFF_W1T  400192    // bf16[64*256] = 8192 words
#define OFF_DPK  408384    // int[782*16*160 = 2001920] packed (src<<6|dst&63)
#define OFF_SV6  2410304   // uchar[2001920] = 500480 words
#define OFF_CSR  2910784   // int[782*1536 = 1201152]
#define OFF_HF32 4111936   // f32[50000*64] = 3200000 (UN-normed x@W1, fp32)
#define OFF_HB   7311936   // bf16[50000*64] = 1600000 dwords (norm_src-scaled)
#define OFF_H2   8911936   // f32[100000]

typedef __attribute__((ext_vector_type(8))) short bf16x8;
typedef __attribute__((ext_vector_type(4))) float f32x4;

static __device__ __forceinline__ unsigned short f2bf(float f) {
    union { float f; unsigned int u; } v; v.f = f;
    return (unsigned short)((v.u + 0x8000u) >> 16);
}
static __device__ __forceinline__ unsigned int pk2bf(float f0, float f1) {
    union { float f; unsigned int u; } a, b; a.f = f0; b.f = f1;
    return __builtin_amdgcn_perm(b.u + 0x8000u, a.u + 0x8000u, 0x07060302u);
}
static __device__ __forceinline__ float bflo(unsigned int u) {
    union { unsigned int x; float f; } v; v.x = u << 16; return v.f;
}
static __device__ __forceinline__ float bfhi(unsigned int u) {
    union { unsigned int x; float f; } v; v.x = u & 0xffff0000u; return v.f;
}

// K0: zero sub-cursor arrays (contiguous), W1 -> W1T bf16
#define INIT_CUR (2 * NDB * NSUB * CSTR)
#define INIT_N (INIT_CUR + NFEAT * NHID)
__global__ __launch_bounds__(256) void init_kernel(const float* __restrict__ W1,
                                                   int* __restrict__ cursors,
                                                   unsigned short* __restrict__ w1t) {
    int g = blockIdx.x * 256 + threadIdx.x;
    if (g < INIT_CUR) {
        cursors[g] = 0;
    } else if (g < INIT_N) {
        int idx = g - INIT_CUR;
        int k = idx >> 6, n = idx & 63;
        w1t[n * NFEAT + k] = f2bf(W1[idx]);
    }
}

// K1: interleaved roles (bid%5==0 -> scatter, else gemm); 196*5 = 980 blocks.
//  scatter: single-pass binning, 16 edges/thread (EPB=4096 halves the
//           partial-line write amplification and cursor chain depth vs 2048).
//  gemm:    hf32 = x @ W1T, UN-normed fp32 (no fin dependency -> overlaps
//           scatter). LDS-free direct-fragment MFMA, 16 loads prefetched.
struct SgShared { int hd[NDB], bd[NDB], cd[NDB], hs[NDB], bs[NDB], cs[NDB]; };  // 18.8 KB
__global__ __launch_bounds__(256) void sg_kernel(const int* __restrict__ src,
                                                 const int* __restrict__ dst,
                                                 const float* __restrict__ x,
                                                 const unsigned short* __restrict__ w1t,
                                                 int* __restrict__ cur_d,
                                                 int* __restrict__ cur_s,
                                                 int* __restrict__ dpk,
                                                 unsigned char* __restrict__ sv6,
                                                 float* __restrict__ hf32) {
    __shared__ SgShared su;
    int t = threadIdx.x;
    int bid = blockIdx.x;
    if (bid % 5 == 0) {
        // ---- scatter role ----
        int chunk = bid / 5;
        int sub = chunk & (NSUB - 1);
        for (int i = t; i < NDB; i += 256) { su.hd[i] = 0; su.cd[i] = 0; su.hs[i] = 0; su.cs[i] = 0; }
        __syncthreads();
        int base = chunk * EPB;
        int ls[16], ld[16];
#pragma unroll
        for (int i = 0; i < 16; ++i) {
            int e = base + t + i * 256;
            ls[i] = (e < N_EDGES) ? src[e] : -1;
            ld[i] = (e < N_EDGES) ? dst[e] : -1;
            if (ld[i] >= 0) {
                atomicAdd(&su.hd[ld[i] >> 6], 1);
                atomicAdd(&su.hs[ls[i] >> 6], 1);
            }
        }
        __syncthreads();
        for (int i = t; i < NDB; i += 256) {
            if (su.hd[i]) su.bd[i] = atomicAdd(&cur_d[(sub * NDB + i) * CSTR], su.hd[i]);
            if (su.hs[i]) su.bs[i] = atomicAdd(&cur_s[(sub * NDB + i) * CSTR], su.hs[i]);
        }
        __syncthreads();
#pragma unroll
        for (int i = 0; i < 16; ++i) {
            if (ld[i] >= 0) {
                int bin = ld[i] >> 6;
                int pos = su.bd[bin] + atomicAdd(&su.cd[bin], 1);
                dpk[(bin * NSUB + sub) * SUBCAP + pos] = (ls[i] << 6) | (ld[i] & 63);
                int sbin = ls[i] >> 6;
                int spos = su.bs[sbin] + atomicAdd(&su.cs[sbin], 1);
                sv6[(sbin * NSUB + sub) * SUBCAP + spos] = (unsigned char)(ls[i] & 63);
            }
        }
    } else {
        // ---- gemm role ----
        const int g = bid - 1 - bid / 5;               // 0..783 bijective
        if (g >= NDB) return;
        const int row0 = g * 64;
        const int w = t >> 6;
        const int l = t & 63;
        const int m = l & 15;
        const int q = l >> 4;
        int grow = row0 + w * 16 + m;
        const float* xr = &x[(size_t)((grow < N_NODES) ? grow : 0) * NFEAT];
        float4 av[16];
#pragma unroll
        for (int i = 0; i < 8; ++i) {
            av[2 * i]     = *(const float4*)(xr + i * 32 + q * 8);
            av[2 * i + 1] = *(const float4*)(xr + i * 32 + q * 8 + 4);
        }
        f32x4 acc[4] = {{0.f, 0.f, 0.f, 0.f}, {0.f, 0.f, 0.f, 0.f},
                        {0.f, 0.f, 0.f, 0.f}, {0.f, 0.f, 0.f, 0.f}};
#pragma unroll
        for (int c8 = 0; c8 < 8; ++c8) {
            int k0 = c8 * 32 + q * 8;
            union { bf16x8 v; unsigned int u[4]; } a;
            a.u[0] = pk2bf(av[2 * c8].x, av[2 * c8].y);
            a.u[1] = pk2bf(av[2 * c8].z, av[2 * c8].w);
            a.u[2] = pk2bf(av[2 * c8 + 1].x, av[2 * c8 + 1].y);
            a.u[3] = pk2bf(av[2 * c8 + 1].z, av[2 * c8 + 1].w);
#pragma unroll
            for (int ct = 0; ct < 4; ++ct) {
                bf16x8 bb = *(const bf16x8*)(&w1t[(ct * 16 + m) * NFEAT + k0]);
                acc[ct] = __builtin_amdgcn_mfma_f32_16x16x32_bf16(a.v, bb, acc[ct], 0, 0, 0);
            }
        }
#pragma unroll
        for (int reg = 0; reg < 4; ++reg) {
            int r = row0 + w * 16 + q * 4 + reg;
            if (r < N_NODES) {
#pragma unroll
                for (int ct = 0; ct < 4; ++ct)
                    hf32[(size_t)r * NHID + ct * 16 + m] = acc[ct][reg];
            }
        }
    }
}

// K2: two roles:
//  role 0: sfin -- out-degree hist over sv6 sub-ranges -> norm_src; then
//          converts this bucket's hf32 rows -> hb = bf16(ns * hf32)
//          (single rounding; rows just written by sg, L2-hot, contiguous)
//  role 1: dfin -- stage NSUB dpk sub-ranges to LDS, hist/prefix -> CSR
//          + norm_dst/rbdeg
union FinShared {
    struct { int ebuf[BCAP]; int hist4[256]; int hist[64]; int seg[64]; int cur[64]; } d;
    struct { int hist4[256]; float nss[64]; } s;
};
__global__ __launch_bounds__(256) void fin_kernel(const int* __restrict__ cur_d,
                                                  const int* __restrict__ cur_s,
                                                  const int* __restrict__ dpk,
                                                  const unsigned char* __restrict__ sv6,
                                                  const float* __restrict__ hf32,
                                                  int2* __restrict__ rbdeg,
                                                  float* __restrict__ norm_dst,
                                                  float* __restrict__ norm_src,
                                                  int* __restrict__ csr,
                                                  unsigned short* __restrict__ hb) {
    __shared__ FinShared su;
    int t = threadIdx.x;
    int role = blockIdx.x & 1;
    int b = blockIdx.x >> 1;

    if (role == 0) {
        // ---- sfin ----
        su.s.hist4[t] = 0;
        __syncthreads();
        int sub4 = (t & 3) * 64;
        for (int sub = 0; sub < NSUB; ++sub) {
            int c = cur_s[(sub * NDB + b) * CSTR];
            c = (c < SUBCAP) ? c : SUBCAP;
            int gb = (b * NSUB + sub) * SUBCAP;
            for (int j = t; j < c; j += 256) atomicAdd(&su.s.hist4[sub4 + sv6[gb + j]], 1);
        }
        __syncthreads();
        if (t < 64) {
            int gid = b * 64 + t;
            int v = su.s.hist4[t] + su.s.hist4[64 + t] + su.s.hist4[128 + t] + su.s.hist4[192 + t];
            float ns = rsqrtf(fmaxf((float)v, 1.0f));
            su.s.nss[t] = ns;
            if (gid < N_NODES) norm_src[gid] = ns;
        }
        __syncthreads();
        // convert 64 rows of hf32 -> hb, scaled by ns (1024 float4 chunks)
        for (int i = t; i < 1024; i += 256) {
            int n8 = i >> 4;             // node within bucket
            int q = i & 15;              // float4 chunk within row
            int gid = b * 64 + n8;
            if (gid < N_NODES) {
                float s = su.s.nss[n8];
                float4 v = *(const float4*)(&hf32[(size_t)gid * NHID + q * 4]);
                uint2 o;
                o.x = pk2bf(v.x * s, v.y * s);
                o.y = pk2bf(v.z * s, v.w * s);
                *(uint2*)(&hb[(size_t)gid * NHID + q * 4]) = o;
            }
        }
    } else {
        // ---- dfin ----
        int base = b * BCAP;
        if (t < 64) { su.d.hist[t] = 0; su.d.cur[t] = 0; }
        su.d.hist4[t] = 0;
        int off = 0;
        for (int sub = 0; sub < NSUB; ++sub) {
            int c = cur_d[(sub * NDB + b) * CSTR];
            c = (c < SUBCAP) ? c : SUBCAP;
            int gb = (b * NSUB + sub) * SUBCAP;
            for (int j = t; j < c; j += 256) su.d.ebuf[off + j] = dpk[gb + j];
            off += c;
        }
        int cnt = off;
        __syncthreads();
        int sub4 = (t & 3) * 64;
        for (int j = t; j < cnt; j += 256) atomicAdd(&su.d.hist4[sub4 + (su.d.ebuf[j] & 63)], 1);
        __syncthreads();
        if (t < 64) {
            int v = su.d.hist4[t] + su.d.hist4[64 + t] + su.d.hist4[128 + t] + su.d.hist4[192 + t];
            su.d.hist[t] = v;
            su.d.seg[t] = v;
        }
        __syncthreads();
#pragma unroll
        for (int offp = 1; offp < 64; offp <<= 1) {
            int xv = 0;
            if (t < 64 && t >= offp) xv = su.d.seg[t - offp];
            __syncthreads();
            if (t < 64) su.d.seg[t] += xv;
            __syncthreads();
        }
        if (t < 64) {
            int v = su.d.hist[t];
            int excl = su.d.seg[t] - v;
            int gid = b * 64 + t;
            if (gid < N_NODES) {
                rbdeg[gid] = make_int2(base + excl, v);
                norm_dst[gid] = rsqrtf(fmaxf((float)v, 1.0f));
            }
            su.d.seg[t] = excl;
        }
        __syncthreads();
        for (int j = t; j < cnt; j += 256) {
            int p = su.d.ebuf[j];
            int dlow = p & 63;
            int pos = base + su.d.seg[dlow] + atomicAdd(&su.d.cur[dlow], 1);
            csr[pos] = ((unsigned)p) >> 6;
        }
    }
}

// K3: fused layer1, node-major. hb pre-scaled by norm_src -> per-edge work
// is csr load + hb row load + adds. 32 edges in flight per wave.
__global__ __launch_bounds__(256) void fused1_kernel(const int2* __restrict__ rbdeg,
                                                     const int* __restrict__ csr,
                                                     const unsigned short* __restrict__ hb,
                                                     const float* __restrict__ norm_dst,
                                                     const float* __restrict__ norm_src,
                                                     const float* __restrict__ b1,
                                                     const float* __restrict__ W2,
                                                     float* __restrict__ h2) {
    int gtid = blockIdx.x * blockDim.x + threadIdx.x;
    int node = gtid >> 6;
    int lane = gtid & 63;
    if (node >= N_NODES) return;
    int e8 = lane >> 3, fg = lane & 7;
    int2 rd = rbdeg[node];
    int beg = rd.x;
    int end = beg + rd.y;
    float a0 = 0.f, a1 = 0.f, a2 = 0.f, a3 = 0.f, a4 = 0.f, a5 = 0.f, a6 = 0.f, a7 = 0.f;
    for (int j = beg; j < end; j += 32) {
        int j0 = j + e8, j1 = j0 + 8, j2 = j0 + 16, j3 = j0 + 24;
        uint4 u0 = make_uint4(0u, 0u, 0u, 0u), u1 = make_uint4(0u, 0u, 0u, 0u);
        uint4 u2 = make_uint4(0u, 0u, 0u, 0u), u3 = make_uint4(0u, 0u, 0u, 0u);
        if (j0 < end) u0 = *(const uint4*)(&hb[(size_t)csr[j0] * NHID + fg * 8]);
        if (j1 < end) u1 = *(const uint4*)(&hb[(size_t)csr[j1] * NHID + fg * 8]);
        if (j2 < end) u2 = *(const uint4*)(&hb[(size_t)csr[j2] * NHID + fg * 8]);
        if (j3 < end) u3 = *(const uint4*)(&hb[(size_t)csr[j3] * NHID + fg * 8]);
        a0 += bflo(u0.x) + bflo(u1.x) + bflo(u2.x) + bflo(u3.x);
        a1 += bfhi(u0.x) + bfhi(u1.x) + bfhi(u2.x) + bfhi(u3.x);
        a2 += bflo(u0.y) + bflo(u1.y) + bflo(u2.y) + bflo(u3.y);
        a3 += bfhi(u0.y) + bfhi(u1.y) + bfhi(u2.y) + bfhi(u3.y);
        a4 += bflo(u0.z) + bflo(u1.z) + bflo(u2.z) + bflo(u3.z);
        a5 += bfhi(u0.z) + bfhi(u1.z) + bfhi(u2.z) + bfhi(u3.z);
        a6 += bflo(u0.w) + bflo(u1.w) + bflo(u2.w) + bflo(u3.w);
        a7 += bfhi(u0.w) + bfhi(u1.w) + bfhi(u2.w) + bfhi(u3.w);
    }
#pragma unroll
    for (int off = 8; off <= 32; off <<= 1) {
        a0 += __shfl_xor(a0, off, 64);
        a1 += __shfl_xor(a1, off, 64);
        a2 += __shfl_xor(a2, off, 64);
        a3 += __shfl_xor(a3, off, 64);
        a4 += __shfl_xor(a4, off, 64);
        a5 += __shfl_xor(a5, off, 64);
        a6 += __shfl_xor(a6, off, 64);
        a7 += __shfl_xor(a7, off, 64);
    }
    float nd = norm_dst[node], ns = norm_src[node];
    float4 bv0 = *(const float4*)(&b1[fg * 8]);
    float4 bv1 = *(const float4*)(&b1[fg * 8 + 4]);
    float4 w0 = *(const float4*)(&W2[fg * 16 + 0]);
    float4 w1 = *(const float4*)(&W2[fg * 16 + 4]);
    float4 w2v = *(const float4*)(&W2[fg * 16 + 8]);
    float4 w3 = *(const float4*)(&W2[fg * 16 + 12]);
    float h0 = fmaxf(fmaf(a0, nd, bv0.x), 0.f) * ns;
    float h1 = fmaxf(fmaf(a1, nd, bv0.y), 0.f) * ns;
    float h2f = fmaxf(fmaf(a2, nd, bv0.z), 0.f) * ns;
    float h3 = fmaxf(fmaf(a3, nd, bv0.w), 0.f) * ns;
    float h4 = fmaxf(fmaf(a4, nd, bv1.x), 0.f) * ns;
    float h5 = fmaxf(fmaf(a5, nd, bv1.y), 0.f) * ns;
    float h6 = fmaxf(fmaf(a6, nd, bv1.z), 0.f) * ns;
    float h7 = fmaxf(fmaf(a7, nd, bv1.w), 0.f) * ns;
    float p0 = h0 * w0.x + h1 * w0.z + h2f * w1.x + h3 * w1.z +
               h4 * w2v.x + h5 * w2v.z + h6 * w3.x + h7 * w3.z;
    float p1 = h0 * w0.y + h1 * w0.w + h2f * w1.y + h3 * w1.w +
               h4 * w2v.y + h5 * w2v.w + h6 * w3.y + h7 * w3.w;
#pragma unroll
    for (int off = 1; off <= 4; off <<= 1) {
        p0 += __shfl_xor(p0, off, 64);
        p1 += __shfl_xor(p1, off, 64);
    }
    if (lane == 0) *(float2*)(&h2[node * 2]) = make_float2(p0, p1);
}

// K4: fused layer2: one 16-lane group per node, shfl reduce, log_softmax.
__global__ __launch_bounds__(256) void fused2_kernel(const int2* __restrict__ rbdeg,
                                                     const int* __restrict__ csr,
                                                     const float* __restrict__ h2,
                                                     const float* __restrict__ norm_dst,
                                                     const float* __restrict__ b2,
                                                     float* __restrict__ out) {
    int gtid = blockIdx.x * blockDim.x + threadIdx.x;
    int n = gtid >> 4;
    int l16 = gtid & 15;
    if (n >= N_NODES) return;
    int2 rd = rbdeg[n];
    int beg = rd.x, end = rd.x + rd.y;
    float s0 = 0.f, s1 = 0.f;
    for (int j = beg + l16; j < end; j += 16) {
        float2 v = *(const float2*)(&h2[csr[j] * 2]);
        s0 += v.x;
        s1 += v.y;
    }
#pragma unroll
    for (int off = 1; off <= 8; off <<= 1) {
        s0 += __shfl_xor(s0, off, 16);
        s1 += __shfl_xor(s1, off, 16);
    }
    if (l16 == 0) {
        float nd = norm_dst[n];
        float l0 = fmaf(s0, nd, b2[0]);
        float l1 = fmaf(s1, nd, b2[1]);
        float m = fmaxf(l0, l1);
        float lse = m + logf(expf(l0 - m) + expf(l1 - m));
        *(float2*)(&out[n * 2]) = make_float2(l0 - lse, l1 - lse);
    }
}

extern "C" void kernel_launch(void* const* d_in, const int* in_sizes, int n_in,
                              void* d_out, int out_size, void* d_ws, size_t ws_size,
                              hipStream_t stream) {
    const float* x  = (const float*)d_in[0];
    const int* src  = (const int*)d_in[1];
    const int* dst  = (const int*)d_in[2];
    const float* W1 = (const float*)d_in[3];
    const float* b1 = (const float*)d_in[4];
    const float* W2 = (const float*)d_in[5];
    const float* b2 = (const float*)d_in[6];
    float* out = (float*)d_out;
    float* ws  = (float*)d_ws;
    int*   wsi = (int*)d_ws;

    int*   cur_d    = wsi + OFF_CURD;
    int*   cur_s    = wsi + OFF_CURS;
    int2*  rbdeg    = (int2*)(wsi + OFF_RBD);
    float* norm_dst = ws + OFF_NDST;
    float* norm_src = ws + OFF_NSRC;
    unsigned short* w1t = (unsigned short*)(wsi + OFF_W1T);
    int*   dpk      = wsi + OFF_DPK;
    unsigned char* sv6 = (unsigned char*)(wsi + OFF_SV6);
    int*   csr      = wsi + OFF_CSR;
    float* hf32     = ws + OFF_HF32;
    unsigned short* hb = (unsigned short*)(wsi + OFF_HB);
    float* h2       = ws + OFF_H2;

    init_kernel<<<(INIT_N + 255) / 256, 256, 0, stream>>>(W1, cur_d, w1t);
    sg_kernel<<<NB_EDGE * 5, 256, 0, stream>>>(src, dst, x, w1t, cur_d, cur_s, dpk, sv6, hf32);
    fin_kernel<<<NDB * 2, 256, 0, stream>>>(cur_d, cur_s, dpk, sv6, hf32,
                                            rbdeg, norm_dst, norm_src, csr, hb);
    {
        long long threads = (long long)N_NODES * 64;
        fused1_kernel<<<(int)((threads + 255) / 256), 256, 0, stream>>>(
            rbdeg, csr, hb, norm_dst, norm_src, b1, W2, h2);
    }
    {
        long long threads = (long long)N_NODES * 16;
        fused2_kernel<<<(int)((threads + 255) / 256), 256, 0, stream>>>(
            rbdeg, csr, h2, norm_dst, b2, out);
    }
}